// Round 1
// baseline (294.041 us; speedup 1.0000x reference)
//
#include <hip/hip_runtime.h>
#include <hip/hip_bf16.h>

#define BN   8
#define NN   1024
#define CIN  256
#define COUT 256
#define HH   4
#define CC   64
#define ALPHA_C 0.2f
#define NEG_INF_C (-9000000000000000.0f)

#define ROWS_K1 16
#define ITILE 16
#define JTILE 64

// ---------------- Kernel 1: h = X@W^T + b, plus l_src/l_dst ----------------
__global__ __launch_bounds__(256) void k1_gemm(
    const float* __restrict__ X, const float* __restrict__ W,
    const float* __restrict__ bias, const float* __restrict__ a,
    float* __restrict__ h, float* __restrict__ lsrc, float* __restrict__ ldst)
{
    __shared__ float4 Xs4[ROWS_K1 * 64];   // 16 rows x 256 f32 = 16 KB

    const int row0 = blockIdx.x * ROWS_K1;
    const float4* X4 = (const float4*)(X + (size_t)row0 * CIN);
    for (int v = threadIdx.x; v < ROWS_K1 * 64; v += 256) Xs4[v] = X4[v];
    __syncthreads();

    const int c = threadIdx.x;                    // output channel 0..255
    const float4* W4 = (const float4*)(W + (size_t)c * CIN);

    float acc[ROWS_K1];
    #pragma unroll
    for (int i = 0; i < ROWS_K1; ++i) acc[i] = 0.f;

    for (int k4 = 0; k4 < 64; ++k4) {
        float4 w4 = W4[k4];
        #pragma unroll
        for (int i = 0; i < ROWS_K1; ++i) {
            float4 x4 = Xs4[i * 64 + k4];        // broadcast
            acc[i] += x4.x * w4.x + x4.y * w4.y + x4.z * w4.z + x4.w * w4.w;
        }
    }

    const float bv = bias[c];
    const int hh = c >> 6, cc = c & 63;
    const float asrc = a[hh * (2 * CC) + cc];
    const float adst = a[hh * (2 * CC) + CC + cc];
    const int lane = threadIdx.x & 63;

    #pragma unroll
    for (int i = 0; i < ROWS_K1; ++i) {
        float v = acc[i] + bv;
        h[(size_t)(row0 + i) * COUT + c] = v;
        float s1 = v * asrc, s2 = v * adst;
        #pragma unroll
        for (int off = 32; off >= 1; off >>= 1) {
            s1 += __shfl_xor(s1, off);
            s2 += __shfl_xor(s2, off);
        }
        if (lane == 0) {
            lsrc[(size_t)(row0 + i) * HH + hh] = s1;
            ldst[(size_t)(row0 + i) * HH + hh] = s2;
        }
    }
}

// ---------------- Kernel 2: masked softmax attention + PV ----------------
// grid: B * (N/ITILE) blocks, 256 threads.
// Phase 1 mapping: wave = head (tid>>6), lane = jl (tid&63)
// Phase 2 mapping: wave w owns il = w*4..w*4+3; lane: h2 = (tid&63)>>4, c4 = tid&15
__global__ __launch_bounds__(256) void k2_attn(
    const float* __restrict__ h, const int* __restrict__ adj,
    const float* __restrict__ lsrc_g, const float* __restrict__ ldst_g,
    float* __restrict__ out)
{
    __shared__ float ldst_s[HH * NN];          // [h][j]  16 KB
    __shared__ float lsrc_s[HH * ITILE];       // [h][il]
    __shared__ float p_s[JTILE * 65];          // [jl]*65 + il*4 + h  (pad 65: conflict-free)
    __shared__ float factor_s[ITILE * HH];     // [il][h]
    __shared__ float lsum_s[ITILE * HH];       // [il][h]

    const int bidx = blockIdx.x;
    const int b  = bidx >> 6;                  // N/ITILE = 64 tiles per batch
    const int i0 = (bidx & 63) * ITILE;
    const int tid = threadIdx.x;

    for (int idx = tid; idx < HH * NN; idx += 256) {
        int hh = idx >> 10, j = idx & 1023;
        ldst_s[idx] = ldst_g[((size_t)b * NN + j) * HH + hh];
    }
    if (tid < ITILE * HH) {
        int il = tid >> 2, hh = tid & 3;
        lsrc_s[hh * ITILE + il] = lsrc_g[((size_t)(b * NN + i0 + il)) * HH + hh];
    }
    __syncthreads();

    const int hw = tid >> 6;       // phase-1 head
    const int jl = tid & 63;       // phase-1 lane j
    const int h2 = (tid & 63) >> 4; // phase-2 head
    const int c4 = tid & 15;        // phase-2 c-quad
    const int w  = tid >> 6;        // phase-2 il-group

    float m[ITILE], lsum[ITILE];
    #pragma unroll
    for (int il = 0; il < ITILE; ++il) { m[il] = NEG_INF_C; lsum[il] = 0.f; }
    float4 acc[4];
    #pragma unroll
    for (int q = 0; q < 4; ++q) acc[q] = make_float4(0.f, 0.f, 0.f, 0.f);

    const int*   adj_b = adj + (size_t)b * NN * NN;
    const float* h_b   = h   + (size_t)b * NN * COUT;

    for (int j0 = 0; j0 < NN; j0 += JTILE) {
        // ---------------- phase 1: logits + online softmax ----------------
        const float ldv = ldst_s[hw * NN + j0 + jl];
        const int* adj_p = adj_b + (size_t)i0 * NN + j0 + jl;
        #pragma unroll
        for (int il = 0; il < ITILE; ++il) {
            int av = adj_p[il * NN];
            float s = lsrc_s[hw * ITILE + il] + ldv;
            s = (s > 0.f) ? s : ALPHA_C * s;
            s = av ? s : NEG_INF_C;
            float tmax = s;
            #pragma unroll
            for (int off = 32; off >= 1; off >>= 1)
                tmax = fmaxf(tmax, __shfl_xor(tmax, off));
            float mnew = fmaxf(m[il], tmax);
            float fac = __expf(m[il] - mnew);
            float pj  = __expf(s - mnew);
            float ts = pj;
            #pragma unroll
            for (int off = 32; off >= 1; off >>= 1)
                ts += __shfl_xor(ts, off);
            lsum[il] = lsum[il] * fac + ts;
            m[il] = mnew;
            p_s[jl * 65 + il * 4 + hw] = pj;
            if (jl == 0) factor_s[il * 4 + hw] = fac;
        }
        __syncthreads();

        // ---------------- phase 2: acc = acc*fac + P @ h_tile ----------------
        #pragma unroll
        for (int q = 0; q < 4; ++q) {
            float fac = factor_s[(w * 4 + q) * 4 + h2];
            acc[q].x *= fac; acc[q].y *= fac; acc[q].z *= fac; acc[q].w *= fac;
        }
        #pragma unroll 4
        for (int jj = 0; jj < JTILE; ++jj) {
            float4 hv = ((const float4*)(h_b + (size_t)(j0 + jj) * COUT))[h2 * 16 + c4];
            #pragma unroll
            for (int q = 0; q < 4; ++q) {
                float pv = p_s[jj * 65 + (w * 4 + q) * 4 + h2];
                acc[q].x += pv * hv.x; acc[q].y += pv * hv.y;
                acc[q].z += pv * hv.z; acc[q].w += pv * hv.w;
            }
        }
        __syncthreads();   // before next tile overwrites p_s
    }

    if (jl == 0) {
        #pragma unroll
        for (int il = 0; il < ITILE; ++il) lsum_s[il * 4 + hw] = lsum[il];
    }
    __syncthreads();

    #pragma unroll
    for (int q = 0; q < 4; ++q) {
        int il = w * 4 + q;
        float inv = 1.0f / lsum_s[il * 4 + h2];
        float4 o;
        o.x = acc[q].x * inv; o.y = acc[q].y * inv;
        o.z = acc[q].z * inv; o.w = acc[q].w * inv;
        ((float4*)(out + (size_t)(b * NN + i0 + il) * COUT))[h2 * 16 + c4] = o;
    }
}

extern "C" void kernel_launch(void* const* d_in, const int* in_sizes, int n_in,
                              void* d_out, int out_size, void* d_ws, size_t ws_size,
                              hipStream_t stream) {
    const float* X    = (const float*)d_in[0];
    const int*   adj  = (const int*)  d_in[1];
    const float* W    = (const float*)d_in[2];
    const float* bias = (const float*)d_in[3];
    const float* a    = (const float*)d_in[4];
    float* out = (float*)d_out;

    float* h    = (float*)d_ws;                        // B*N*COUT f32 = 8 MB
    float* lsrc = h    + (size_t)BN * NN * COUT;       // B*N*H
    float* ldst = lsrc + (size_t)BN * NN * HH;         // B*N*H

    k1_gemm<<<(BN * NN) / ROWS_K1, 256, 0, stream>>>(X, W, bias, a, h, lsrc, ldst);
    k2_attn<<<BN * (NN / ITILE), 256, 0, stream>>>(h, adj, lsrc, ldst, out);
}